// Round 4
// baseline (375.675 us; speedup 1.0000x reference)
//
#include <hip/hip_runtime.h>
#include <type_traits>

#define NBATCH 32
#define NDIM 512
#define NFAST 448

// ---- DPP cross-lane primitives (VALU-speed; no LDS, no barriers) ----

template <int CTRL, int RMASK>
__device__ __forceinline__ float dpp_add(float x) {
  int t = __builtin_amdgcn_update_dpp(0, __float_as_int(x), CTRL, RMASK, 0xf,
                                      false);
  return x + __int_as_float(t);
}

// wave64 inclusive prefix sum
__device__ __forceinline__ float prefix_inc(float x) {
  x = dpp_add<0x111, 0xf>(x);  // row_shr:1
  x = dpp_add<0x112, 0xf>(x);  // row_shr:2
  x = dpp_add<0x114, 0xf>(x);  // row_shr:4
  x = dpp_add<0x118, 0xf>(x);  // row_shr:8
  x = dpp_add<0x142, 0xa>(x);  // row_bcast:15 -> rows 1,3
  x = dpp_add<0x143, 0xc>(x);  // row_bcast:31 -> rows 2,3
  return x;
}

// shift one lane up (lane i gets lane i-1); lane 0 receives `fill`
__device__ __forceinline__ float wave_shr1(float x, float fill) {
  return __int_as_float(__builtin_amdgcn_update_dpp(
      __float_as_int(fill), __float_as_int(x), 0x138 /*wave_shr:1*/, 0xf, 0xf,
      false));
}

// one step of the wave64 inclusive affine-composition scan.
// Compose earlier-then-later: B = A*Be + B ; A = A*Ae. Identity = (1,0).
template <int CTRL, int RMASK>
__device__ __forceinline__ void aff_step(float& A, float& B) {
  float Ae = __int_as_float(__builtin_amdgcn_update_dpp(
      __float_as_int(1.0f), __float_as_int(A), CTRL, RMASK, 0xf, false));
  float Be = __int_as_float(__builtin_amdgcn_update_dpp(
      0, __float_as_int(B), CTRL, RMASK, 0xf, false));
  B = fmaf(A, Be, B);
  A = A * Ae;
}

// Workgroup barrier WITHOUT the vmcnt(0) drain __syncthreads() emits.
__device__ __forceinline__ void wg_barrier() {
  asm volatile("s_waitcnt lgkmcnt(0)" ::: "memory");
  __builtin_amdgcn_s_barrier();
  asm volatile("" ::: "memory");
}

// Validate a prefetched record: spin-reload until its seq field == m.
// Steady state: producer published a full systolic step earlier, so the
// first read is already valid and the loop never iterates.
__device__ __forceinline__ float4 lds_wait_rec(float4 r, const float4* p,
                                               int m) {
  while (__builtin_expect(__float_as_int(r.w) != m, 0)) {
    __builtin_amdgcn_s_sleep(1);
    asm volatile("" ::: "memory");  // force a fresh ds_read_b128
    r = *p;
  }
  return r;
}

// R17: barrier-FREE systolic skew. Wave w processes row m at step
// t = m + w. Cross-wave inputs for row m were produced >= 1 full step
// earlier; ordering comes from LDS's per-wave in-order DS completion:
// the producer writes {A,B,PA} early in its step and the seq word after
// the ~20-instruction tail, so a reader that sees seq==m is guaranteed
// valid data — no fence, no barrier, no writer-side lgkmcnt stall.
// Consumers validate seq with a spin that never iterates in steady
// state (write-once table => producers never wait; drift self-limits).
// Math is bit-identical to R14/R16 fast rows (same uin, predicates, E
// chain) => absmax unchanged. FULL rows (448..511, backward suffix dep)
// keep the R14 2-barrier body; its first barrier de-skews the waves.
__global__ __launch_bounds__(256, 1)
void sb_kernel(const float* __restrict__ x, const float* __restrict__ xm,
               float* __restrict__ out) {
  const int tid = (int)threadIdx.x;
  const int lane = tid & 63;
  const int w = __builtin_amdgcn_readfirstlane(tid >> 6);  // wave id 0..3
  const size_t base =
      (size_t)blockIdx.x * NDIM * NDIM + (size_t)(w * 128 + lane * 2);
  const float* xb = x + base;
  const float* mb = xm + base;
  float* ob = out + base;

  __shared__ float4 recs[NFAST][3];       // 21 KB write-once {A,B,PA,seq}
  __shared__ alignas(16) float ex_sa[4];  // FULL-mode barrier exchange
  __shared__ alignas(16) float ex_S[4];
  __shared__ alignas(16) float ex_A[4];
  __shared__ alignas(16) float ex_B[4];

  // per-lane state for the 2 owned columns
  float w8_0, w8_1, t8_0, t8_1, pre1, sa;
  float fu0 = 0.0f, fu1 = 0.0f, suf0 = 0.0f, S = 0.0f;
  float wp0, wp1, sp0 = 0.0f, sp1 = 0.0f;
  float c1_0, c1_1, c2_0, c2_1, oc2_0, oc2_1;

  // ---- initial loads: row 0 direct; rows 1..3 into t-indexed slots ----
  // Slot discipline: at step t (unrolled position r = t&3) a wave loads
  // row m+4 into slot r and prep-consumes row m+1 from slot (r+1)&3.
  // Initial fill: row r0 lands in slot (w+r0)&3.
  float2 X0 = *(const float2*)(xb);
  float2 M0 = *(const float2*)(mb);
  float2 a1 = *(const float2*)(xb + NDIM), b1 = *(const float2*)(mb + NDIM);
  float2 a2 = *(const float2*)(xb + 2 * NDIM),
         b2 = *(const float2*)(mb + 2 * NDIM);
  float2 a3 = *(const float2*)(xb + 3 * NDIM),
         b3 = *(const float2*)(mb + 3 * NDIM);
  float2 sx0 = a1, sm0 = b1, sx1 = a1, sm1 = b1, sx2 = a1, sm2 = b1, sx3 = a1,
         sm3 = b1;
  switch (w) {
    case 0:
      sx1 = a1; sm1 = b1; sx2 = a2; sm2 = b2; sx3 = a3; sm3 = b3;
      break;
    case 1:
      sx2 = a1; sm2 = b1; sx3 = a2; sm3 = b2; sx0 = a3; sm0 = b3;
      break;
    case 2:
      sx3 = a1; sm3 = b1; sx0 = a2; sm0 = b2; sx1 = a3; sm1 = b3;
      break;
    default:
      sx0 = a1; sm0 = b1; sx1 = a2; sm1 = b2; sx2 = a3; sm2 = b3;
      break;
  }

  // init record seq fields to -1 (LDS content undefined at start), then
  // one-time sync so no wave reads uninitialized seq words.
  for (int j = tid; j < NFAST * 3; j += 256)
    *(volatile int*)&(((float*)recs)[4 * j + 3]) = -1;
  wg_barrier();

  auto build_pre = [&]() {
    pre1 = t8_0;
    sa = t8_0 + t8_1;
    wp0 = w8_0;         // w8 + pre(=0)
    wp1 = w8_1 + pre1;  // w8 + pre
  };
  auto build_suf = [&]() {
    suf0 = fu1;  // suf[1] = 0
    S = fu0 + fu1;
    sp0 = suf0;  // suf + pre(=0)
    sp1 = pre1;  // suf(=0) + pre
  };

  {  // row-0 prep: constants + scan inputs (w == 1, cs == 0)
    float s0 = __builtin_amdgcn_rcpf(1.0f + __expf(-X0.x));
    float s1 = __builtin_amdgcn_rcpf(1.0f + __expf(-X0.y));
    c2_0 = M0.x * s0;
    c2_1 = M0.y * s1;
    oc2_0 = 1.0f - c2_0;
    oc2_1 = 1.0f - c2_1;
    c1_0 = M0.x - c2_0;
    c1_1 = M0.y - c2_1;
    w8_0 = 1.0f;
    w8_1 = 1.0f;
    t8_0 = c2_0;
    t8_1 = c2_1;
    build_pre();
  }

  // ---- barrier-free systolic fast step ----
  auto fast_step = [&](int t, float2& LXx, float2& LXm, const float2& CXx,
                       const float2& CXm) {
    const int m = t - w;
    if ((unsigned)m < (unsigned)NFAST) {  // wave-uniform
      // issue predecessor record reads (published >=1 step ago)
      float4 r0, r1, r2;
      if (w > 0) r0 = *(const float4*)&recs[m][0];
      if (w > 1) r1 = *(const float4*)&recs[m][1];
      if (w > 2) r2 = *(const float4*)&recs[m][2];
      // issue next-row global load (m+4 <= 451, no wrap needed)
      const size_t nro = (size_t)(m + 4) * NDIM;
      LXx = *(const float2*)(xb + nro);
      LXm = *(const float2*)(mb + nro);

      // local prefix scan (chain head; covers record-read latency)
      float PA = prefix_inc(sa);

      // row m+1 x-only prep (data loaded 3 steps ago; off-chain)
      float sg0 = __builtin_amdgcn_rcpf(1.0f + __expf(-CXx.x));
      float sg1 = __builtin_amdgcn_rcpf(1.0f + __expf(-CXx.y));
      float c2n0 = CXm.x * sg0;
      float c2n1 = CXm.y * sg1;
      float oc2n0 = 1.0f - c2n0;
      float oc2n1 = 1.0f - c2n1;
      float c1n0 = CXm.x - c2n0;
      float c1n1 = CXm.y - c2n1;

      // validate + consume cross-wave inputs (same order as R14/R16)
      float off_sa = 0.0f;
      float E = 1.0f;
      if (w > 0) {
        r0 = lds_wait_rec(r0, &recs[m][0], m);
        off_sa += r0.z;
        E = fmaf(r0.x, E, r0.y);
      }
      if (w > 1) {
        r1 = lds_wait_rec(r1, &recs[m][1], m);
        off_sa += r1.z;
        E = fmaf(r1.x, E, r1.y);
      }
      if (w > 2) {
        r2 = lds_wait_rec(r2, &recs[m][2], m);
        off_sa += r2.z;
        E = fmaf(r2.x, E, r2.y);
      }
      float uin = fmaxf(1.0f - (off_sa + (PA - sa)), 0.0f);

      // parallel branch prediction (2 cells)
      bool pW0 = wp0 < uin;
      bool pW1 = wp1 < uin;
      float aP0 = pW0 ? 1.0f : oc2_0;
      float aP1 = pW1 ? 1.0f : oc2_1;
      float bP0 = pW0 ? (-t8_0) : 0.0f;
      float bP1 = pW1 ? (-t8_1) : 0.0f;

      // pair compose + wave affine scan
      float A = aP1 * aP0;
      float Bv = fmaf(aP1, bP0, bP1);
      aff_step<0x111, 0xf>(A, Bv);
      aff_step<0x112, 0xf>(A, Bv);
      aff_step<0x114, 0xf>(A, Bv);
      aff_step<0x118, 0xf>(A, Bv);
      aff_step<0x142, 0xa>(A, Bv);
      aff_step<0x143, 0xc>(A, Bv);
      float Aex = wave_shr1(A, 1.0f);
      float Bex = wave_shr1(Bv, 0.0f);

      // publish data words EARLY (seq follows after the tail; per-wave
      // DS ops complete in order, so seq==m implies data valid)
      if (w < 3 && lane == 63) {
        recs[m][w].x = A;
        recs[m][w].y = Bv;
        recs[m][w].z = PA;
      }
      asm volatile("" ::: "memory");  // compile-time: data before seq

      float e = fminf(fmaxf(fmaf(Aex, E, Bex), 0.0f), 1.0f);  // lane entry

      // within-lane entries + TRUE-branch outputs (g==0 on fast rows)
      float uu0 = e;
      float uu1 = fmaxf(fmaf(aP0, e, bP0), 0.0f);
      float U0 = fminf(uu0, w8_0);
      float U1 = fminf(uu1, w8_1);
      float p0 = c2_0 * U0;
      float p1 = c2_1 * U1;
      w8_0 -= p0;
      w8_1 -= p1;
      *(float2*)(ob + (size_t)m * NDIM) = make_float2(p0, p1);

      // next row's scan inputs (the real cross-row chain)
      t8_0 = c2n0 * w8_0;
      t8_1 = c2n1 * w8_1;
      build_pre();
      c2_0 = c2n0;
      c2_1 = c2n1;
      oc2_0 = oc2n0;
      oc2_1 = oc2n1;
      c1_0 = c1n0;
      c1_1 = c1n1;

      // publish seq word LAST (in-order DS => data already committed)
      if (w < 3 && lane == 63) {
        asm volatile("" ::: "memory");
        *(volatile int*)&recs[m][w].w = m;
      }
    }
  };

  // fast phase: steps t = 0 .. 451 (wave w active for t in [w, w+448))
#pragma unroll 1
  for (int t = 0; t < NFAST + 4; t += 4) {
    fast_step(t + 0, sx0, sm0, sx1, sm1);
    fast_step(t + 1, sx1, sm1, sx2, sm2);
    fast_step(t + 2, sx2, sm2, sx3, sm3);
    fast_step(t + 3, sx3, sm3, sx0, sm0);
  }

  // de-skew before the FULL phase's shared ex_* exchanges
  wg_barrier();

  // ---- bridge: rebuild fu/S/suf/sp for row 448 and reload rows
  // 449..451 into canonical slots (L2-hot, one-time) ----
  sx1 = *(const float2*)(xb + (size_t)449 * NDIM);
  sm1 = *(const float2*)(mb + (size_t)449 * NDIM);
  sx2 = *(const float2*)(xb + (size_t)450 * NDIM);
  sm2 = *(const float2*)(mb + (size_t)450 * NDIM);
  sx3 = *(const float2*)(xb + (size_t)451 * NDIM);
  sm3 = *(const float2*)(mb + (size_t)451 * NDIM);
  {
    float om0 = 1.0f - c1_0 - c2_0;
    float om1 = 1.0f - c1_1 - c2_1;
    fu0 = fmaxf(w8_0 - om0, 0.0f);
    fu1 = fmaxf(w8_1 - om1, 0.0f);
    build_suf();
  }

  // ---- FULL row body: R14 2-barrier structure (backward dep on S) ----
  auto row_full = [&](int m, float2& WX, float2& WM, const float2& RX,
                      const float2& RM) {
    const size_t nro = (size_t)((m + 4) & (NDIM - 1)) * NDIM;
    WX = *(const float2*)(xb + nro);
    WM = *(const float2*)(mb + nro);

    // local wave scans (chain head)
    float PS = prefix_inc(S);
    float PA = prefix_inc(sa);

    if (lane == 63) {
      ex_sa[w] = PA;  // wave-inclusive total
      ex_S[w] = PS;
    }
    wg_barrier();  // bar1: publish scan totals

    float4 sav = *(const float4*)ex_sa;
    float off_sa = 0.0f;
    if (w > 0) off_sa += sav.x;
    if (w > 1) off_sa += sav.y;
    if (w > 2) off_sa += sav.z;
    float uin = fmaxf(1.0f - (off_sa + (PA - sa)), 0.0f);

    float4 Sv = *(const float4*)ex_S;
    float Tg = (Sv.x + Sv.y) + (Sv.z + Sv.w);
    float off_S = 0.0f;
    if (w > 0) off_S += Sv.x;
    if (w > 1) off_S += Sv.y;
    if (w > 2) off_S += Sv.z;
    float R_ = (Tg - off_S) - PS;  // future mass strictly after this lane
    float mfm0 = R_ + suf0;
    float mfm1 = R_;  // suf[1] = 0
    float nc1m0 = -c1_0 * mfm0;
    float nc1m1 = -c1_1 * mfm1;

    // parallel branch prediction (2 cells)
    bool pW0 = wp0 < uin;
    bool pW1 = wp1 < uin;
    float aP0 = pW0 ? 1.0f : oc2_0;
    float aP1 = pW1 ? 1.0f : oc2_1;
    float bP0 = pW0 ? (-t8_0) : 0.0f;
    float bP1 = pW1 ? (-t8_1) : 0.0f;
    float d = uin - R_;
    bool pL0 = d > sp0;
    bool pL1 = d > sp1;
    if (pL0) {
      aP0 -= c1_0;
      bP0 -= nc1m0;
    }
    if (pL1) {
      aP1 -= c1_1;
      bP1 -= nc1m1;
    }

    // pair compose + wave affine scan
    float A = aP1 * aP0;
    float Bv = fmaf(aP1, bP0, bP1);
    aff_step<0x111, 0xf>(A, Bv);
    aff_step<0x112, 0xf>(A, Bv);
    aff_step<0x114, 0xf>(A, Bv);
    aff_step<0x118, 0xf>(A, Bv);
    aff_step<0x142, 0xa>(A, Bv);
    aff_step<0x143, 0xc>(A, Bv);
    float Aex = wave_shr1(A, 1.0f);
    float Bex = wave_shr1(Bv, 0.0f);

    if (lane == 63) {
      ex_A[w] = A;  // wave-inclusive composition
      ex_B[w] = Bv;
    }
    wg_barrier();  // bar2: publish affine totals

    float4 eAv = *(const float4*)ex_A;
    float4 eBv = *(const float4*)ex_B;
    float E = 1.0f;
    if (w > 0) E = fmaf(eAv.x, E, eBv.x);
    if (w > 1) E = fmaf(eAv.y, E, eBv.y);
    if (w > 2) E = fmaf(eAv.z, E, eBv.z);
    float e = fminf(fmaxf(fmaf(Aex, E, Bex), 0.0f), 1.0f);  // lane entry

    // row m+1 x-only prep
    float c1n0, c1n1, c2n0, c2n1, oc2n0, oc2n1, omn0, omn1;
    {
      float s0 = __builtin_amdgcn_rcpf(1.0f + __expf(-RX.x));
      float s1 = __builtin_amdgcn_rcpf(1.0f + __expf(-RX.y));
      c2n0 = RM.x * s0;
      c2n1 = RM.y * s1;
      oc2n0 = 1.0f - c2n0;
      oc2n1 = 1.0f - c2n1;
      c1n0 = RM.x - c2n0;
      c1n1 = RM.y - c2n1;
      omn0 = 1.0f - RM.x;
      omn1 = 1.0f - RM.y;
    }

    // within-lane entries + TRUE-branch outputs
    float uu0 = e;
    float uu1 = fmaxf(fmaf(aP0, e, bP0), 0.0f);
    float U0 = fminf(uu0, w8_0);
    float U1 = fminf(uu1, w8_1);
    float g0 = fmaxf(fmaf(c1_0, uu0, nc1m0), 0.0f);
    float g1 = fmaxf(fmaf(c1_1, uu1, nc1m1), 0.0f);
    float p0 = fmaf(c2_0, U0, g0);
    float p1 = fmaf(c2_1, U1, g1);
    w8_0 -= p0;
    w8_1 -= p1;
    *(float2*)(ob + (size_t)m * NDIM) = make_float2(p0, p1);

    // next row's scan inputs
    t8_0 = c2n0 * w8_0;
    t8_1 = c2n1 * w8_1;
    build_pre();
    fu0 = fmaxf(w8_0 - omn0, 0.0f);
    fu1 = fmaxf(w8_1 - omn1, 0.0f);
    build_suf();
    c2_0 = c2n0;
    c2_1 = c2n1;
    oc2_0 = oc2n0;
    oc2_1 = oc2n1;
    c1_0 = c1n0;
    c1_1 = c1n1;
  };

#pragma unroll 1
  for (int m = NFAST; m < NDIM; m += 4) {
    row_full(m + 0, sx0, sm0, sx1, sm1);
    row_full(m + 1, sx1, sm1, sx2, sm2);
    row_full(m + 2, sx2, sm2, sx3, sm3);
    row_full(m + 3, sx3, sm3, sx0, sm0);
  }
}

extern "C" void kernel_launch(void* const* d_in, const int* in_sizes, int n_in,
                              void* d_out, int out_size, void* d_ws,
                              size_t ws_size, hipStream_t stream) {
  const float* x = (const float*)d_in[0];
  const float* xmask = (const float*)d_in[1];
  float* out = (float*)d_out;
  (void)in_sizes;
  (void)n_in;
  (void)out_size;
  (void)d_ws;
  (void)ws_size;
  hipLaunchKernelGGL(sb_kernel, dim3(NBATCH), dim3(256), 0, stream, x, xmask,
                     out);
}

// Round 5
// 293.835 us; speedup vs baseline: 1.2785x; 1.2785x over previous
//
#include <hip/hip_runtime.h>
#include <type_traits>

#define NBATCH 32
#define NDIM 512
#define NFAST 448
#define NWAVE 8

// ---- DPP cross-lane primitives (VALU-speed; no LDS, no barriers) ----

template <int CTRL, int RMASK>
__device__ __forceinline__ float dpp_add(float x) {
  int t = __builtin_amdgcn_update_dpp(0, __float_as_int(x), CTRL, RMASK, 0xf,
                                      false);
  return x + __int_as_float(t);
}

// wave64 inclusive prefix sum
__device__ __forceinline__ float prefix_inc(float x) {
  x = dpp_add<0x111, 0xf>(x);  // row_shr:1
  x = dpp_add<0x112, 0xf>(x);  // row_shr:2
  x = dpp_add<0x114, 0xf>(x);  // row_shr:4
  x = dpp_add<0x118, 0xf>(x);  // row_shr:8
  x = dpp_add<0x142, 0xa>(x);  // row_bcast:15 -> rows 1,3
  x = dpp_add<0x143, 0xc>(x);  // row_bcast:31 -> rows 2,3
  return x;
}

// shift one lane up (lane i gets lane i-1); lane 0 receives `fill`
__device__ __forceinline__ float wave_shr1(float x, float fill) {
  return __int_as_float(__builtin_amdgcn_update_dpp(
      __float_as_int(fill), __float_as_int(x), 0x138 /*wave_shr:1*/, 0xf, 0xf,
      false));
}

// one step of the wave64 inclusive affine-composition scan.
// Compose earlier-then-later: B = A*Be + B ; A = A*Ae. Identity = (1,0).
template <int CTRL, int RMASK>
__device__ __forceinline__ void aff_step(float& A, float& B) {
  float Ae = __int_as_float(__builtin_amdgcn_update_dpp(
      __float_as_int(1.0f), __float_as_int(A), CTRL, RMASK, 0xf, false));
  float Be = __int_as_float(__builtin_amdgcn_update_dpp(
      0, __float_as_int(B), CTRL, RMASK, 0xf, false));
  B = fmaf(A, Be, B);
  A = A * Ae;
}

// Workgroup barrier WITHOUT the vmcnt(0) drain __syncthreads() emits.
// Writer-side LDS ordering via lgkmcnt(0); trailing empty asm with a
// memory clobber stops the compiler hoisting post-barrier LDS reads.
// Global prefetch loads stay in flight across step barriers.
__device__ __forceinline__ void wg_barrier() {
  asm volatile("s_waitcnt lgkmcnt(0)" ::: "memory");
  __builtin_amdgcn_s_barrier();
  asm volatile("" ::: "memory");
}

// R18: 8-wave systolic with cumulative rolling records. Wave w owns
// columns [64w, 64w+64), lane owns exactly 1 column. Systolic skew:
// wave w processes row m at step t = m + w, one barrier per step (the
// R16 scheme — proven >= spin alternatives). Cross-wave coupling is a
// SINGLE rolling LDS cell per row: recs[m] holds the cumulative
// {A,B,PA} of waves 0..k after wave k's step. Wave w reads cum(0..w-1)
// (published >= 1 step earlier, visible via the step barrier), uses
// r.z as its global prefix offset and r.x+r.y as its row-entry E, and
// publishes cum(0..w) = compose(r, own). Consume is O(1) in wave
// count, enabling 8 waves: body shrinks ~2x (no within-lane pair
// work), and 2 waves/SIMD at DIFFERENT rows interleave — the first
// real latency hiding in this kernel family. FULL rows (448..511,
// backward suffix dep) keep the 2-barrier exchange, widened to 8.
__global__ __launch_bounds__(512, 2)
void sb_kernel(const float* __restrict__ x, const float* __restrict__ xm,
               float* __restrict__ out) {
  const int tid = (int)threadIdx.x;
  const int lane = tid & 63;
  const int w = __builtin_amdgcn_readfirstlane(tid >> 6);  // wave id 0..7
  const size_t base =
      (size_t)blockIdx.x * NDIM * NDIM + (size_t)(w * 64 + lane);
  const float* xb = x + base;
  const float* mb = xm + base;
  float* ob = out + base;

  __shared__ float4 recs[NFAST];  // 7 KB rolling cumulative {A,B,PA,-}
  __shared__ alignas(16) float ex_sa[NWAVE];  // FULL-mode exchange
  __shared__ alignas(16) float ex_S[NWAVE];
  __shared__ alignas(16) float ex_A[NWAVE];
  __shared__ alignas(16) float ex_B[NWAVE];

  // per-lane state for the single owned column
  float w8, t8, sa;
  float fu = 0.0f, S = 0.0f;
  float c1, c2, oc2;

  // ---- initial loads: row 0 direct; rows 1..3 into t-indexed slots ----
  // Slot discipline: at step t (r = t&3) a wave loads row m+4 into slot
  // r and prep-consumes row m+1 from slot (r+1)&3. Row r0 initially
  // lands in slot (w + r0) & 3 (mapping depends only on w&3).
  float X0 = *(xb);
  float M0 = *(mb);
  float a1 = xb[NDIM], b1 = mb[NDIM];
  float a2 = xb[2 * NDIM], b2 = mb[2 * NDIM];
  float a3 = xb[3 * NDIM], b3 = mb[3 * NDIM];
  float sx0 = a1, sm0 = b1, sx1 = a1, sm1 = b1, sx2 = a1, sm2 = b1, sx3 = a1,
        sm3 = b1;
  switch (w & 3) {
    case 0:
      sx1 = a1; sm1 = b1; sx2 = a2; sm2 = b2; sx3 = a3; sm3 = b3;
      break;
    case 1:
      sx2 = a1; sm2 = b1; sx3 = a2; sm3 = b2; sx0 = a3; sm0 = b3;
      break;
    case 2:
      sx3 = a1; sm3 = b1; sx0 = a2; sm0 = b2; sx1 = a3; sm1 = b3;
      break;
    default:
      sx0 = a1; sm0 = b1; sx1 = a2; sm1 = b2; sx2 = a3; sm2 = b3;
      break;
  }

  {  // row-0 prep: constants + scan inputs (w8 == 1, cs == 0)
    float sg = __builtin_amdgcn_rcpf(1.0f + __expf(-X0));
    c2 = M0 * sg;
    oc2 = 1.0f - c2;
    c1 = M0 - c2;
    w8 = 1.0f;
    t8 = c2;
    sa = t8;
  }

  // ---- systolic fast step: one barrier, O(1) cum consume ----
  auto fast_step = [&](int t, float& LX, float& LM, const float& CX,
                       const float& CM) {
    const int m = t - w;
    if ((unsigned)m < (unsigned)NFAST) {  // wave-uniform
      // read predecessor cum (published >= 1 step ago; identity for w=0)
      float4 r = make_float4(1.0f, 0.0f, 0.0f, 0.0f);
      if (w > 0) r = recs[m];  // broadcast LDS read, issued at step start
      // issue next-row global load (m+4 <= 451, no wrap needed)
      const size_t nro = (size_t)(m + 4) * NDIM;
      LX = xb[nro];
      LM = mb[nro];

      // local prefix scan (chain head; covers record-read latency)
      float PA = prefix_inc(sa);

      // row m+1 x-only prep (data loaded 3+ steps ago; off-chain)
      float sg = __builtin_amdgcn_rcpf(1.0f + __expf(-CX));
      float c2n = CM * sg;
      float oc2n = 1.0f - c2n;
      float c1n = CM - c2n;

      // linear entry guess: 1 - global exclusive t8-prefix before lane
      float uin = fmaxf(1.0f - (r.z + (PA - sa)), 0.0f);

      // branch prediction (1 cell) -> affine piece
      bool pW = w8 < uin;
      float A = pW ? 1.0f : oc2;
      float Bv = pW ? (-t8) : 0.0f;

      // wave affine scan
      aff_step<0x111, 0xf>(A, Bv);
      aff_step<0x112, 0xf>(A, Bv);
      aff_step<0x114, 0xf>(A, Bv);
      aff_step<0x118, 0xf>(A, Bv);
      aff_step<0x142, 0xa>(A, Bv);
      aff_step<0x143, 0xc>(A, Bv);
      float Aex = wave_shr1(A, 1.0f);
      float Bex = wave_shr1(Bv, 0.0f);

      // publish cum(0..w) for the successor (lane 63 holds wave totals;
      // ordering to next step via the wg_barrier's lgkmcnt(0)+barrier)
      if (w < NWAVE - 1 && lane == 63)
        recs[m] = make_float4(A * r.x, fmaf(A, r.y, Bv), r.z + PA, 0.0f);

      // row entry into this wave = cum applied to 1.0
      float E = r.x + r.y;
      float e = fminf(fmaxf(fmaf(Aex, E, Bex), 0.0f), 1.0f);  // lane entry

      // output (g == 0 provably on fast rows)
      float p = c2 * fminf(e, w8);
      w8 -= p;
      ob[(size_t)m * NDIM] = p;

      // next row's scan inputs (the real cross-row chain)
      t8 = c2n * w8;
      sa = t8;
      c2 = c2n;
      oc2 = oc2n;
      c1 = c1n;
    }
    wg_barrier();
  };

  // fast phase: steps t = 0 .. 455 (wave w active for t in [w, w+448))
#pragma unroll 1
  for (int t = 0; t < NFAST + NWAVE; t += 4) {
    fast_step(t + 0, sx0, sm0, sx1, sm1);
    fast_step(t + 1, sx1, sm1, sx2, sm2);
    fast_step(t + 2, sx2, sm2, sx3, sm3);
    fast_step(t + 3, sx3, sm3, sx0, sm0);
  }
  // all waves synced by the final step barrier; recs no longer used

  // ---- bridge: rebuild fu/S for row 448; reload rows 449..451 into
  // canonical slots (L2-hot, one-time) ----
  sx1 = xb[(size_t)449 * NDIM];
  sm1 = mb[(size_t)449 * NDIM];
  sx2 = xb[(size_t)450 * NDIM];
  sm2 = mb[(size_t)450 * NDIM];
  sx3 = xb[(size_t)451 * NDIM];
  sm3 = mb[(size_t)451 * NDIM];
  {
    float om = 1.0f - c1 - c2;  // 1 - mask(row 448)
    fu = fmaxf(w8 - om, 0.0f);
    S = fu;
  }

  // ---- FULL row body: 2-barrier exchange (backward dep on S) ----
  auto row_full = [&](int m, float& WX, float& WM, const float& RX,
                      const float& RM) {
    const size_t nro = (size_t)((m + 4) & (NDIM - 1)) * NDIM;
    WX = xb[nro];
    WM = mb[nro];

    // local wave scans (chain head)
    float PS = prefix_inc(S);
    float PA = prefix_inc(sa);

    if (lane == 63) {
      ex_sa[w] = PA;  // wave-inclusive totals
      ex_S[w] = PS;
    }
    wg_barrier();  // bar1: publish scan totals

    float4 sl = *(const float4*)&ex_sa[0];
    float4 sh = *(const float4*)&ex_sa[4];
    float4 Sl = *(const float4*)&ex_S[0];
    float4 Sh = *(const float4*)&ex_S[4];
    float off_sa = 0.0f, off_S = 0.0f;
    if (w > 0) { off_sa += sl.x; off_S += Sl.x; }
    if (w > 1) { off_sa += sl.y; off_S += Sl.y; }
    if (w > 2) { off_sa += sl.z; off_S += Sl.z; }
    if (w > 3) { off_sa += sl.w; off_S += Sl.w; }
    if (w > 4) { off_sa += sh.x; off_S += Sh.x; }
    if (w > 5) { off_sa += sh.y; off_S += Sh.y; }
    if (w > 6) { off_sa += sh.z; off_S += Sh.z; }
    float Tg = ((Sl.x + Sl.y) + (Sl.z + Sl.w)) + ((Sh.x + Sh.y) + (Sh.z + Sh.w));

    float uin = fmaxf(1.0f - (off_sa + (PA - sa)), 0.0f);
    float R_ = (Tg - off_S) - PS;  // future mass strictly after this lane
    float nc1m = -c1 * R_;         // per-lane suf == 0 at 1 col/lane

    // branch prediction (1 cell)
    bool pW = w8 < uin;  // wp = w8 (pre == 0)
    float aP = pW ? 1.0f : oc2;
    float bP = pW ? (-t8) : 0.0f;
    bool pL = (uin - R_) > 0.0f;  // sp == 0
    if (pL) {
      aP -= c1;
      bP -= nc1m;
    }

    // wave affine scan
    float A = aP, Bv = bP;
    aff_step<0x111, 0xf>(A, Bv);
    aff_step<0x112, 0xf>(A, Bv);
    aff_step<0x114, 0xf>(A, Bv);
    aff_step<0x118, 0xf>(A, Bv);
    aff_step<0x142, 0xa>(A, Bv);
    aff_step<0x143, 0xc>(A, Bv);
    float Aex = wave_shr1(A, 1.0f);
    float Bex = wave_shr1(Bv, 0.0f);

    if (lane == 63) {
      ex_A[w] = A;  // wave-inclusive composition
      ex_B[w] = Bv;
    }
    wg_barrier();  // bar2: publish affine totals

    float4 Al = *(const float4*)&ex_A[0];
    float4 Ah = *(const float4*)&ex_A[4];
    float4 Bl = *(const float4*)&ex_B[0];
    float4 Bh = *(const float4*)&ex_B[4];
    float E = 1.0f;
    if (w > 0) E = fmaf(Al.x, E, Bl.x);
    if (w > 1) E = fmaf(Al.y, E, Bl.y);
    if (w > 2) E = fmaf(Al.z, E, Bl.z);
    if (w > 3) E = fmaf(Al.w, E, Bl.w);
    if (w > 4) E = fmaf(Ah.x, E, Bh.x);
    if (w > 5) E = fmaf(Ah.y, E, Bh.y);
    if (w > 6) E = fmaf(Ah.z, E, Bh.z);
    float e = fminf(fmaxf(fmaf(Aex, E, Bex), 0.0f), 1.0f);  // lane entry

    // row m+1 x-only prep (off-chain)
    float sg = __builtin_amdgcn_rcpf(1.0f + __expf(-RX));
    float c2n = RM * sg;
    float oc2n = 1.0f - c2n;
    float c1n = RM - c2n;
    float omn = 1.0f - RM;

    // TRUE-branch output
    float U = fminf(e, w8);
    float g = fmaxf(fmaf(c1, e, nc1m), 0.0f);
    float p = fmaf(c2, U, g);
    w8 -= p;
    ob[(size_t)m * NDIM] = p;

    // next row's scan inputs
    t8 = c2n * w8;
    sa = t8;
    fu = fmaxf(w8 - omn, 0.0f);
    S = fu;
    c2 = c2n;
    oc2 = oc2n;
    c1 = c1n;
  };

#pragma unroll 1
  for (int m = NFAST; m < NDIM; m += 4) {
    row_full(m + 0, sx0, sm0, sx1, sm1);
    row_full(m + 1, sx1, sm1, sx2, sm2);
    row_full(m + 2, sx2, sm2, sx3, sm3);
    row_full(m + 3, sx3, sm3, sx0, sm0);
  }
}

extern "C" void kernel_launch(void* const* d_in, const int* in_sizes, int n_in,
                              void* d_out, int out_size, void* d_ws,
                              size_t ws_size, hipStream_t stream) {
  const float* x = (const float*)d_in[0];
  const float* xmask = (const float*)d_in[1];
  float* out = (float*)d_out;
  (void)in_sizes;
  (void)n_in;
  (void)out_size;
  (void)d_ws;
  (void)ws_size;
  hipLaunchKernelGGL(sb_kernel, dim3(NBATCH), dim3(512), 0, stream, x, xmask,
                     out);
}

// Round 7
// 271.599 us; speedup vs baseline: 1.3832x; 1.0819x over previous
//
#include <hip/hip_runtime.h>

#define NBATCH 32
#define NDIM 512
#define NFAST 448
#define NPAIR 224
#define NWAVE 8

// ---- DPP cross-lane primitives (VALU-speed; no LDS, no barriers) ----

template <int CTRL, int RMASK>
__device__ __forceinline__ float dpp_add(float x) {
  int t = __builtin_amdgcn_update_dpp(0, __float_as_int(x), CTRL, RMASK, 0xf,
                                      false);
  return x + __int_as_float(t);
}

// wave64 inclusive prefix sum
__device__ __forceinline__ float prefix_inc(float x) {
  x = dpp_add<0x111, 0xf>(x);  // row_shr:1
  x = dpp_add<0x112, 0xf>(x);  // row_shr:2
  x = dpp_add<0x114, 0xf>(x);  // row_shr:4
  x = dpp_add<0x118, 0xf>(x);  // row_shr:8
  x = dpp_add<0x142, 0xa>(x);  // row_bcast:15 -> rows 1,3
  x = dpp_add<0x143, 0xc>(x);  // row_bcast:31 -> rows 2,3
  return x;
}

// shift one lane up (lane i gets lane i-1); lane 0 receives `fill`
__device__ __forceinline__ float wave_shr1(float x, float fill) {
  return __int_as_float(__builtin_amdgcn_update_dpp(
      __float_as_int(fill), __float_as_int(x), 0x138 /*wave_shr:1*/, 0xf, 0xf,
      false));
}

// one step of the wave64 inclusive affine-composition scan.
// Compose earlier-then-later: B = A*Be + B ; A = A*Ae. Identity = (1,0).
template <int CTRL, int RMASK>
__device__ __forceinline__ void aff_step(float& A, float& B) {
  float Ae = __int_as_float(__builtin_amdgcn_update_dpp(
      __float_as_int(1.0f), __float_as_int(A), CTRL, RMASK, 0xf, false));
  float Be = __int_as_float(__builtin_amdgcn_update_dpp(
      0, __float_as_int(B), CTRL, RMASK, 0xf, false));
  B = fmaf(A, Be, B);
  A = A * Ae;
}

// Workgroup barrier WITHOUT the vmcnt(0) drain __syncthreads() emits.
// Writer-side LDS ordering via lgkmcnt(0); trailing empty asm with a
// memory clobber stops the compiler hoisting post-barrier LDS reads.
// Global prefetch loads stay in flight across step barriers.
__device__ __forceinline__ void wg_barrier() {
  asm volatile("s_waitcnt lgkmcnt(0)" ::: "memory");
  __builtin_amdgcn_s_barrier();
  asm volatile("" ::: "memory");
}

// R20: R18's 8-wave systolic (PROVEN math, bit-identical here) with TWO
// rows per step to amortize the ~600cy/step barrier+latency overhead.
// Wave w owns cols [64w,64w+64), lane owns 1 col. Wave w processes row
// pair {2s, 2s+1} at step t = s + w; one barrier per step (= per 2
// rows). Both predecessor cum records (rows 2s, 2s+1, rolling {A,B,cumPA}
// in recs[]) were published >= 1 full step earlier -> same systolic
// correctness proof as R18. Per-row math (guess scan, predicates, affine
// scan, outputs) is R18 verbatim in the same order => absmax unchanged.
// Addressing strength-reduced to running pointers (R19's safe part).
// FULL rows (448+, backward suffix dep) keep R18's 2-barrier body.
__global__ __launch_bounds__(512, 2)
void sb_kernel(const float* __restrict__ x, const float* __restrict__ xm,
               float* __restrict__ out) {
  const int tid = (int)threadIdx.x;
  const int lane = tid & 63;
  const int w = __builtin_amdgcn_readfirstlane(tid >> 6);  // wave id 0..7
  const size_t base =
      (size_t)blockIdx.x * NDIM * NDIM + (size_t)(w * 64 + lane);
  const float* xb = x + base;
  const float* mb = xm + base;
  float* ob = out + base;

  __shared__ float4 recs[NFAST];              // rolling cum {A,B,cumPA,-}
  __shared__ alignas(16) float ex_sa[NWAVE];  // FULL-mode exchange
  __shared__ alignas(16) float ex_S[NWAVE];
  __shared__ alignas(16) float ex_A[NWAVE];
  __shared__ alignas(16) float ex_B[NWAVE];

  // per-lane state
  float w8, t8;                    // stick remainder + next-row scan input
  float c2_0, oc2_0, c2_1, oc2_1;  // current pair's constants (2 rows)
  float c1, c2, oc2;               // FULL-phase per-row constants
  float fu = 0.0f, S = 0.0f;

  // ---- prologue: rows 0,1 direct; pair1(rows2,3), pair2(rows4,5) into
  // w-dependent slots. Slot discipline (3 rotating slots, each holds one
  // PAIR = {x_r0,x_r1,m_r0,m_r1}): at step t (unroll pos k=t%3) a wave
  // writes pair s+3 into slot[k] and preps pair s+1 from slot[(k+1)%3].
  // Wave w first preps pair1 at t=w from slot[(w+1)%3], pair2 at t=w+1
  // from slot[(w+2)%3]. ----
  float X0 = xb[0], M0 = mb[0];
  float X1 = xb[NDIM], M1 = mb[NDIM];
  float p1x0 = xb[2 * NDIM], p1x1 = xb[3 * NDIM];
  float p1m0 = mb[2 * NDIM], p1m1 = mb[3 * NDIM];
  float p2x0 = xb[4 * NDIM], p2x1 = xb[5 * NDIM];
  float p2m0 = mb[4 * NDIM], p2m1 = mb[5 * NDIM];

  float Ax0, Ax1, Am0, Am1;  // slot 0
  float Bx0, Bx1, Bm0, Bm1;  // slot 1
  float Cx0, Cx1, Cm0, Cm1;  // slot 2
  // default-init all (values unused before overwrite, but keep defined)
  Ax0 = Bx0 = Cx0 = p1x0;
  Ax1 = Bx1 = Cx1 = p1x1;
  Am0 = Bm0 = Cm0 = p1m0;
  Am1 = Bm1 = Cm1 = p1m1;
  switch (w % 3) {
    case 0:  // pair1 -> slot1, pair2 -> slot2
      Bx0 = p1x0; Bx1 = p1x1; Bm0 = p1m0; Bm1 = p1m1;
      Cx0 = p2x0; Cx1 = p2x1; Cm0 = p2m0; Cm1 = p2m1;
      break;
    case 1:  // pair1 -> slot2, pair2 -> slot0
      Cx0 = p1x0; Cx1 = p1x1; Cm0 = p1m0; Cm1 = p1m1;
      Ax0 = p2x0; Ax1 = p2x1; Am0 = p2m0; Am1 = p2m1;
      break;
    default:  // pair1 -> slot0, pair2 -> slot1
      Ax0 = p1x0; Ax1 = p1x1; Am0 = p1m0; Am1 = p1m1;
      Bx0 = p2x0; Bx1 = p2x1; Bm0 = p2m0; Bm1 = p2m1;
      break;
  }

  {  // prep rows 0,1 constants; row-0 scan input (w8 == 1)
    float sg0 = __builtin_amdgcn_rcpf(1.0f + __expf(-X0));
    c2_0 = M0 * sg0;
    oc2_0 = 1.0f - c2_0;
    float sg1 = __builtin_amdgcn_rcpf(1.0f + __expf(-X1));
    c2_1 = M1 * sg1;
    oc2_1 = 1.0f - c2_1;
    w8 = 1.0f;
    t8 = c2_0;
  }

  // running pointers (strength-reduced addressing; only dereferenced when
  // the wave is active, i.e. in-range)
  const float* px = xb + (long)(6 - 2 * w) * NDIM;  // load row 2s+6 at t
  const float* pm = mb + (long)(6 - 2 * w) * NDIM;
  float* po = ob - (long)(2 * w) * NDIM;  // store row 2s at t

  // ---- one row of R18-verbatim math (guess scan + affine scan) ----
  auto row_fast = [&](int m, const float4& r, float c2r, float oc2r,
                      float* pO) {
    float PA = prefix_inc(t8);
    float uin = fmaxf(1.0f - (r.z + (PA - t8)), 0.0f);
    bool pW = w8 < uin;
    float A = pW ? 1.0f : oc2r;
    float Bv = pW ? (-t8) : 0.0f;
    aff_step<0x111, 0xf>(A, Bv);
    aff_step<0x112, 0xf>(A, Bv);
    aff_step<0x114, 0xf>(A, Bv);
    aff_step<0x118, 0xf>(A, Bv);
    aff_step<0x142, 0xa>(A, Bv);
    aff_step<0x143, 0xc>(A, Bv);
    float Aex = wave_shr1(A, 1.0f);
    float Bex = wave_shr1(Bv, 0.0f);
    if (w < NWAVE - 1 && lane == 63)
      recs[m] = make_float4(A * r.x, fmaf(A, r.y, Bv), r.z + PA, 0.0f);
    float E = r.x + r.y;
    float e = fminf(fmaxf(fmaf(Aex, E, Bex), 0.0f), 1.0f);
    float p = c2r * fminf(e, w8);
    w8 -= p;
    *pO = p;
  };

  // ---- 2-row systolic step: one barrier per pair ----
  auto pair_step = [&](int t, int k, float& WX0, float& WX1, float& WM0,
                       float& WM1, const float& RX0, const float& RX1,
                       const float& RM0, const float& RM1) {
    const int s = t - w;
    if ((unsigned)s < (unsigned)NPAIR) {  // wave-uniform
      const int m = 2 * s;
      // read both predecessor cum records (published >= 1 step ago)
      float4 r0 = make_float4(1.0f, 0.0f, 0.0f, 0.0f), r1 = r0;
      if (w > 0) {
        r0 = recs[m];
        r1 = recs[m + 1];
      }
      // issue next pair's global loads (pair s+3, rows 2s+6, 2s+7)
      const float* pxk = px + (size_t)(2 * k) * NDIM;
      const float* pmk = pm + (size_t)(2 * k) * NDIM;
      float LX0 = pxk[0], LX1 = pxk[NDIM];
      float LM0 = pmk[0], LM1 = pmk[NDIM];

      // prep pair s+1 (data loaded 2 steps ago; off-chain)
      float sg0 = __builtin_amdgcn_rcpf(1.0f + __expf(-RX0));
      float c2n0 = RM0 * sg0;
      float oc2n0 = 1.0f - c2n0;
      float sg1 = __builtin_amdgcn_rcpf(1.0f + __expf(-RX1));
      float c2n1 = RM1 * sg1;
      float oc2n1 = 1.0f - c2n1;

      float* pok = po + (size_t)(2 * k) * NDIM;
      // row 2s
      row_fast(m, r0, c2_0, oc2_0, pok);
      t8 = c2_1 * w8;
      // row 2s+1
      row_fast(m + 1, r1, c2_1, oc2_1, pok + NDIM);
      // next pair's scan input + constants
      t8 = c2n0 * w8;
      c2_0 = c2n0;
      oc2_0 = oc2n0;
      c2_1 = c2n1;
      oc2_1 = oc2n1;
      WX0 = LX0;
      WX1 = LX1;
      WM0 = LM0;
      WM1 = LM1;
    }
    wg_barrier();
  };

  // fast phase: steps t = 0 .. 230 (wave w active for t in [w, w+224))
#pragma unroll 1
  for (int t = 0; t < NPAIR + NWAVE - 1; t += 3) {
    pair_step(t + 0, 0, Ax0, Ax1, Am0, Am1, Bx0, Bx1, Bm0, Bm1);
    pair_step(t + 1, 1, Bx0, Bx1, Bm0, Bm1, Cx0, Cx1, Cm0, Cm1);
    pair_step(t + 2, 2, Cx0, Cx1, Cm0, Cm1, Ax0, Ax1, Am0, Am1);
    px += 6 * NDIM;
    pm += 6 * NDIM;
    po += 6 * NDIM;
  }
  // all waves synced by the final step barrier; recs no longer used.
  // c2_0/oc2_0 now hold row-448 constants (prepped at s=223).

  // ---- bridge: row-448 constants + fu/S; reload rows 449..451 into
  // FULL-phase single-row slots (L2-hot, one-time). t8 already =
  // c2(448) * w8 from the last fast step. ----
  float fx0, fm0, fx1, fm1, fx2, fm2, fx3, fm3;
  {
    float m448 = mb[(size_t)448 * NDIM];
    fx1 = xb[(size_t)449 * NDIM];
    fm1 = mb[(size_t)449 * NDIM];
    fx2 = xb[(size_t)450 * NDIM];
    fm2 = mb[(size_t)450 * NDIM];
    fx3 = xb[(size_t)451 * NDIM];
    fm3 = mb[(size_t)451 * NDIM];
    fx0 = fx1;  // defined; overwritten at m=448 step
    fm0 = fm1;
    c2 = c2_0;
    oc2 = oc2_0;
    c1 = m448 - c2;
    float om = 1.0f - m448;
    fu = fmaxf(w8 - om, 0.0f);
    S = fu;
  }

  // ---- FULL row body: R18-verbatim 2-barrier exchange ----
  auto row_full = [&](int m, float& WX, float& WM, const float& RX,
                      const float& RM) {
    const size_t nro = (size_t)((m + 4) & (NDIM - 1)) * NDIM;
    WX = xb[nro];
    WM = mb[nro];

    // local wave scans (chain head)
    float PS = prefix_inc(S);
    float PA = prefix_inc(t8);

    if (lane == 63) {
      ex_sa[w] = PA;  // wave-inclusive totals
      ex_S[w] = PS;
    }
    wg_barrier();  // bar1: publish scan totals

    float4 sl = *(const float4*)&ex_sa[0];
    float4 sh = *(const float4*)&ex_sa[4];
    float4 Sl = *(const float4*)&ex_S[0];
    float4 Sh = *(const float4*)&ex_S[4];
    float off_sa = 0.0f, off_S = 0.0f;
    if (w > 0) { off_sa += sl.x; off_S += Sl.x; }
    if (w > 1) { off_sa += sl.y; off_S += Sl.y; }
    if (w > 2) { off_sa += sl.z; off_S += Sl.z; }
    if (w > 3) { off_sa += sl.w; off_S += Sl.w; }
    if (w > 4) { off_sa += sh.x; off_S += Sh.x; }
    if (w > 5) { off_sa += sh.y; off_S += Sh.y; }
    if (w > 6) { off_sa += sh.z; off_S += Sh.z; }
    float Tg =
        ((Sl.x + Sl.y) + (Sl.z + Sl.w)) + ((Sh.x + Sh.y) + (Sh.z + Sh.w));

    float uin = fmaxf(1.0f - (off_sa + (PA - t8)), 0.0f);
    float R_ = (Tg - off_S) - PS;  // future mass strictly after this lane
    float nc1m = -c1 * R_;         // per-lane suf == 0 at 1 col/lane

    // branch prediction (1 cell)
    bool pW = w8 < uin;
    float aP = pW ? 1.0f : oc2;
    float bP = pW ? (-t8) : 0.0f;
    bool pL = (uin - R_) > 0.0f;
    if (pL) {
      aP -= c1;
      bP -= nc1m;
    }

    // wave affine scan
    float A = aP, Bv = bP;
    aff_step<0x111, 0xf>(A, Bv);
    aff_step<0x112, 0xf>(A, Bv);
    aff_step<0x114, 0xf>(A, Bv);
    aff_step<0x118, 0xf>(A, Bv);
    aff_step<0x142, 0xa>(A, Bv);
    aff_step<0x143, 0xc>(A, Bv);
    float Aex = wave_shr1(A, 1.0f);
    float Bex = wave_shr1(Bv, 0.0f);

    if (lane == 63) {
      ex_A[w] = A;  // wave-inclusive composition
      ex_B[w] = Bv;
    }
    wg_barrier();  // bar2: publish affine totals

    float4 Al = *(const float4*)&ex_A[0];
    float4 Ah = *(const float4*)&ex_A[4];
    float4 Bl = *(const float4*)&ex_B[0];
    float4 Bh = *(const float4*)&ex_B[4];
    float E = 1.0f;
    if (w > 0) E = fmaf(Al.x, E, Bl.x);
    if (w > 1) E = fmaf(Al.y, E, Bl.y);
    if (w > 2) E = fmaf(Al.z, E, Bl.z);
    if (w > 3) E = fmaf(Al.w, E, Bl.w);
    if (w > 4) E = fmaf(Ah.x, E, Bh.x);
    if (w > 5) E = fmaf(Ah.y, E, Bh.y);
    if (w > 6) E = fmaf(Ah.z, E, Bh.z);
    float e = fminf(fmaxf(fmaf(Aex, E, Bex), 0.0f), 1.0f);  // lane entry

    // row m+1 x-only prep (off-chain)
    float sg = __builtin_amdgcn_rcpf(1.0f + __expf(-RX));
    float c2n = RM * sg;
    float oc2n = 1.0f - c2n;
    float c1n = RM - c2n;
    float omn = 1.0f - RM;

    // TRUE-branch output
    float U = fminf(e, w8);
    float g = fmaxf(fmaf(c1, e, nc1m), 0.0f);
    float p = fmaf(c2, U, g);
    w8 -= p;
    ob[(size_t)m * NDIM] = p;

    // next row's scan inputs
    t8 = c2n * w8;
    fu = fmaxf(w8 - omn, 0.0f);
    S = fu;
    c2 = c2n;
    oc2 = oc2n;
    c1 = c1n;
  };

#pragma unroll 1
  for (int m = NFAST; m < NDIM; m += 4) {
    row_full(m + 0, fx0, fm0, fx1, fm1);
    row_full(m + 1, fx1, fm1, fx2, fm2);
    row_full(m + 2, fx2, fm2, fx3, fm3);
    row_full(m + 3, fx3, fm3, fx0, fm0);
  }
}

extern "C" void kernel_launch(void* const* d_in, const int* in_sizes, int n_in,
                              void* d_out, int out_size, void* d_ws,
                              size_t ws_size, hipStream_t stream) {
  const float* x = (const float*)d_in[0];
  const float* xmask = (const float*)d_in[1];
  float* out = (float*)d_out;
  (void)in_sizes;
  (void)n_in;
  (void)out_size;
  (void)d_ws;
  (void)ws_size;
  hipLaunchKernelGGL(sb_kernel, dim3(NBATCH), dim3(512), 0, stream, x, xmask,
                     out);
}